// Round 1
// baseline (532.332 us; speedup 1.0000x reference)
//
#include <hip/hip_runtime.h>
#include <cstdint>
#include <cstddef>

#define B_   64
#define T_   200
#define NQ_  13523
#define NTOK (B_*T_)   // 12800

// ws layout (float offsets)
#define O_MKT  0          // Mkt[128][64]
#define O_EWT  8192       // eWt[128][128]
#define O_AWT  24576      // aWt[128][128]
#define O_FWT  40960      // fWt[256][128]  (c-major)
#define O_W    73728      // w[NTOK][64]
#define O_EV   892928     // e[NTOK][128]
#define O_AV   2531328    // a[NTOK][128]
#define O_KF   4169728    // kf[NTOK][128]
#define O_PART 5808128    // partial[4][NTOK][128]
// total = 12,361,728 floats = 49.4 MB

#define TOKA 32
#define LSTR 36           // padded LDS row stride (floats); 16B-aligned, 8-way wr conflict only

__device__ __forceinline__ float sigmoidf_(float x){ return 1.f/(1.f + __expf(-x)); }

__global__ __launch_bounds__(256) void k_prep(const float* __restrict__ Mk,
    const float* __restrict__ eW, const float* __restrict__ aW,
    const float* __restrict__ fW, float* __restrict__ ws)
{
  int i = blockIdx.x*256 + threadIdx.x;
  if (i < 8192){  int j = i>>6, m = i&63;  ws[O_MKT+i] = Mk[m*128 + j]; }
  if (i < 16384){ int j = i>>7, d = i&127; ws[O_EWT+i] = eW[d*128 + j];
                                           ws[O_AWT+i] = aW[d*128 + j]; }
  if (i < 32768){ int c = i>>7, d = i&127; ws[O_FWT+i] = fW[d*256 + c]; }
}

// 32 tokens/block. Gathers K,V rows into transposed LDS tiles, then:
//   w = softmax(K @ Mk^T)   (lane = m, 8 items/wave, wave-shuffle softmax)
//   e = sigmoid(V @ eW^T + eb), a = tanh(V @ aW^T + ab), kf = K @ fW[:,128:]^T
__global__ __launch_bounds__(256) void k_embed(const int* __restrict__ q,
    const int* __restrict__ r, const float* __restrict__ kE,
    const float* __restrict__ vE, const float* __restrict__ eb,
    const float* __restrict__ ab, float* __restrict__ ws)
{
  __shared__ float Kt[128*LSTR];   // Kt[j][i] : K transposed
  __shared__ float Vt[128*LSTR];
  __shared__ int qx[2*TOKA];
  const int tid = threadIdx.x;
  const int it0 = blockIdx.x * TOKA;

  if (tid < TOKA){
    int qq = q[it0+tid];
    qx[tid]      = qq;
    qx[TOKA+tid] = qq + NQ_*r[it0+tid];
  }
  __syncthreads();

  {
    const int j  = tid & 127;
    const int wg = tid >> 7;
    #pragma unroll
    for (int rr=0; rr<4; ++rr){
      const int i0 = rr*8 + wg*4;
      float4 kv, vv;
      kv.x = kE[(size_t)qx[i0+0]*128 + j];
      kv.y = kE[(size_t)qx[i0+1]*128 + j];
      kv.z = kE[(size_t)qx[i0+2]*128 + j];
      kv.w = kE[(size_t)qx[i0+3]*128 + j];
      vv.x = vE[(size_t)qx[TOKA+i0+0]*128 + j];
      vv.y = vE[(size_t)qx[TOKA+i0+1]*128 + j];
      vv.z = vE[(size_t)qx[TOKA+i0+2]*128 + j];
      vv.w = vE[(size_t)qx[TOKA+i0+3]*128 + j];
      *(float4*)&Kt[j*LSTR + i0] = kv;
      *(float4*)&Vt[j*LSTR + i0] = vv;
    }
  }
  __syncthreads();

  const int lane = tid & 63;
  const int wv   = tid >> 6;     // wave id: items wv*8 .. wv*8+7

  // ---- logits + softmax -> w  (lane = m) ----
  {
    float acc[8] = {0,0,0,0,0,0,0,0};
    #pragma unroll 4
    for (int j=0;j<128;++j){
      float mk  = ws[O_MKT + j*64 + lane];
      float4 k0 = *(const float4*)&Kt[j*LSTR + wv*8];
      float4 k1 = *(const float4*)&Kt[j*LSTR + wv*8 + 4];
      acc[0] = fmaf(k0.x, mk, acc[0]);
      acc[1] = fmaf(k0.y, mk, acc[1]);
      acc[2] = fmaf(k0.z, mk, acc[2]);
      acc[3] = fmaf(k0.w, mk, acc[3]);
      acc[4] = fmaf(k1.x, mk, acc[4]);
      acc[5] = fmaf(k1.y, mk, acc[5]);
      acc[6] = fmaf(k1.z, mk, acc[6]);
      acc[7] = fmaf(k1.w, mk, acc[7]);
    }
    #pragma unroll
    for (int ii=0;ii<8;++ii){
      float x = acc[ii];
      float mx = x;
      #pragma unroll
      for (int off=32; off>0; off>>=1) mx = fmaxf(mx, __shfl_xor(mx, off));
      float ex = __expf(x - mx);
      float sm = ex;
      #pragma unroll
      for (int off=32; off>0; off>>=1) sm += __shfl_xor(sm, off);
      ws[O_W + (size_t)(it0 + wv*8 + ii)*64 + lane] = ex/sm;
    }
  }

  // ---- e, a, kf  (thread covers d0=lane, d1=lane+64; 8 items) ----
  {
    const int d0 = lane, d1 = lane + 64;
    float aE0[8]={0},aE1[8]={0},aA0[8]={0},aA1[8]={0},aK0[8]={0},aK1[8]={0};
    #pragma unroll 2
    for (int j=0;j<128;++j){
      float we0 = ws[O_EWT + j*128 + d0];
      float we1 = ws[O_EWT + j*128 + d1];
      float wa0 = ws[O_AWT + j*128 + d0];
      float wa1 = ws[O_AWT + j*128 + d1];
      float wf0 = ws[O_FWT + (128+j)*128 + d0];
      float wf1 = ws[O_FWT + (128+j)*128 + d1];
      float4 v0 = *(const float4*)&Vt[j*LSTR + wv*8];
      float4 v1 = *(const float4*)&Vt[j*LSTR + wv*8 + 4];
      float4 k0 = *(const float4*)&Kt[j*LSTR + wv*8];
      float4 k1 = *(const float4*)&Kt[j*LSTR + wv*8 + 4];
      float vv[8] = {v0.x,v0.y,v0.z,v0.w,v1.x,v1.y,v1.z,v1.w};
      float kk[8] = {k0.x,k0.y,k0.z,k0.w,k1.x,k1.y,k1.z,k1.w};
      #pragma unroll
      for (int ii=0;ii<8;++ii){
        aE0[ii] = fmaf(vv[ii], we0, aE0[ii]);
        aE1[ii] = fmaf(vv[ii], we1, aE1[ii]);
        aA0[ii] = fmaf(vv[ii], wa0, aA0[ii]);
        aA1[ii] = fmaf(vv[ii], wa1, aA1[ii]);
        aK0[ii] = fmaf(kk[ii], wf0, aK0[ii]);
        aK1[ii] = fmaf(kk[ii], wf1, aK1[ii]);
      }
    }
    const float eb0 = eb[d0], eb1 = eb[d1];
    const float ab0 = ab[d0], ab1 = ab[d1];
    #pragma unroll
    for (int ii=0;ii<8;++ii){
      size_t it = (size_t)(it0 + wv*8 + ii);
      ws[O_EV + it*128 + d0] = sigmoidf_(aE0[ii] + eb0);
      ws[O_EV + it*128 + d1] = sigmoidf_(aE1[ii] + eb1);
      ws[O_AV + it*128 + d0] = tanhf(aA0[ii] + ab0);
      ws[O_AV + it*128 + d1] = tanhf(aA1[ii] + ab1);
      ws[O_KF + it*128 + d0] = aK0[ii];
      ws[O_KF + it*128 + d1] = aK1[ii];
    }
  }
}

// One block per (b, m-chunk of 16). State s[8] per thread (d=tid&127, mg=tid>>7).
// Writes Mv (the 421 MB output) nontemporally; emits per-chunk partial read sums.
__global__ __launch_bounds__(256) void k_scan(const float* __restrict__ Mv0,
    float* __restrict__ ws, float* __restrict__ out)
{
  __shared__ float red[256];
  const int tid = threadIdx.x;
  const int b  = blockIdx.x >> 2;
  const int c  = blockIdx.x & 3;
  const int d  = tid & 127;
  const int mg = tid >> 7;
  const int m0 = c*16 + mg*8;

  float s[8];
  float* mv = out + NTOK + (size_t)b*201*64*128;
  #pragma unroll
  for (int j=0;j<8;++j){
    s[j] = Mv0[(m0+j)*128 + d];
    __builtin_nontemporal_store(s[j], &mv[(size_t)(m0+j)*128 + d]);  // t=0 slice
  }
  const float* wp = ws + O_W  + (size_t)b*T_*64  + m0;
  const float* ep = ws + O_EV + (size_t)b*T_*128 + d;
  const float* ap = ws + O_AV + (size_t)b*T_*128 + d;
  float* pp = ws + O_PART + (size_t)c*NTOK*128 + (size_t)b*T_*128 + tid; // tid<128 only

  float4 wA = *(const float4*)(wp);
  float4 wB = *(const float4*)(wp+4);
  float ec = ep[0];
  float ac = ap[0];
  for (int t=0; t<T_; ++t){
    const int tn = (t < T_-1) ? t+1 : t;
    float4 nA = *(const float4*)(wp + (size_t)tn*64);
    float4 nB = *(const float4*)(wp + (size_t)tn*64 + 4);
    float ne = ep[(size_t)tn*128];
    float na = ap[(size_t)tn*128];

    float w[8] = {wA.x,wA.y,wA.z,wA.w,wB.x,wB.y,wB.z,wB.w};
    float racc = 0.f;
    #pragma unroll
    for (int j=0;j<8;++j) racc = fmaf(w[j], s[j], racc);     // read uses pre-update state
    #pragma unroll
    for (int j=0;j<8;++j){
      float we = w[j]*ec;
      s[j] = fmaf(-we, s[j], fmaf(w[j], ac, s[j]));          // s*(1-we) + w*a
    }
    float* mvt = mv + (size_t)(t+1)*64*128;
    #pragma unroll
    for (int j=0;j<8;++j)
      __builtin_nontemporal_store(s[j], &mvt[(size_t)(m0+j)*128 + d]);

    red[tid] = racc;
    __syncthreads();
    if (tid < 128) pp[(size_t)t*128] = red[tid] + red[tid+128];
    __syncthreads();

    wA=nA; wB=nB; ec=ne; ac=na;
  }
}

// Sum 4 partials -> read; f = tanh(read @ fW[:,:128]^T + kf + fb); p = sigmoid(f.pW + pb)
__global__ __launch_bounds__(256) void k_out(const float* __restrict__ ws,
    const float* __restrict__ fb, const float* __restrict__ pW,
    const float* __restrict__ pb, float* __restrict__ out)
{
  __shared__ float Rt[128*LSTR];
  const int tid = threadIdx.x;
  const int it0 = blockIdx.x * TOKA;
  {
    const int j  = tid & 127;
    const int wg = tid >> 7;
    const float* P = ws + O_PART;
    #pragma unroll
    for (int rr=0; rr<4; ++rr){
      const int i0 = rr*8 + wg*4;
      float v4[4];
      #pragma unroll
      for (int ii=0;ii<4;++ii){
        size_t base = (size_t)(it0+i0+ii)*128 + j;
        v4[ii] = P[base] + P[(size_t)NTOK*128 + base]
               + P[2*(size_t)NTOK*128 + base] + P[3*(size_t)NTOK*128 + base];
      }
      *(float4*)&Rt[j*LSTR + i0] = make_float4(v4[0],v4[1],v4[2],v4[3]);
    }
  }
  __syncthreads();
  const int lane = tid & 63, wv = tid >> 6;
  const int d0 = lane, d1 = lane + 64;
  float a0[8]={0,0,0,0,0,0,0,0}, a1[8]={0,0,0,0,0,0,0,0};
  #pragma unroll 2
  for (int j=0;j<128;++j){
    float w0 = ws[O_FWT + j*128 + d0];
    float w1 = ws[O_FWT + j*128 + d1];
    float4 r0 = *(const float4*)&Rt[j*LSTR + wv*8];
    float4 r1 = *(const float4*)&Rt[j*LSTR + wv*8 + 4];
    float rv[8] = {r0.x,r0.y,r0.z,r0.w,r1.x,r1.y,r1.z,r1.w};
    #pragma unroll
    for (int ii=0;ii<8;++ii){
      a0[ii] = fmaf(rv[ii], w0, a0[ii]);
      a1[ii] = fmaf(rv[ii], w1, a1[ii]);
    }
  }
  const float fb0 = fb[d0], fb1 = fb[d1];
  const float pw0 = pW[d0], pw1 = pW[d1];
  #pragma unroll
  for (int ii=0;ii<8;++ii){
    size_t it = (size_t)(it0 + wv*8 + ii);
    float f0 = tanhf(a0[ii] + ws[O_KF + it*128 + d0] + fb0);
    float f1 = tanhf(a1[ii] + ws[O_KF + it*128 + d1] + fb1);
    float part = fmaf(f0, pw0, f1*pw1);
    #pragma unroll
    for (int off=32; off>0; off>>=1) part += __shfl_xor(part, off);
    if (lane == 0) out[it] = sigmoidf_(part + pb[0]);
  }
}

extern "C" void kernel_launch(void* const* d_in, const int* in_sizes, int n_in,
                              void* d_out, int out_size, void* d_ws, size_t ws_size,
                              hipStream_t stream)
{
  const int*   q   = (const int*)d_in[0];
  const int*   r   = (const int*)d_in[1];
  const float* kE  = (const float*)d_in[2];
  const float* vE  = (const float*)d_in[3];
  const float* Mk  = (const float*)d_in[4];
  const float* Mv0 = (const float*)d_in[5];
  const float* fW  = (const float*)d_in[6];
  const float* fb  = (const float*)d_in[7];
  const float* pW  = (const float*)d_in[8];
  const float* pb  = (const float*)d_in[9];
  const float* eW  = (const float*)d_in[10];
  const float* eb  = (const float*)d_in[11];
  const float* aW  = (const float*)d_in[12];
  const float* ab  = (const float*)d_in[13];
  float* out = (float*)d_out;
  float* ws  = (float*)d_ws;

  k_prep <<<128, 256, 0, stream>>>(Mk, eW, aW, fW, ws);
  k_embed<<<NTOK/TOKA, 256, 0, stream>>>(q, r, kE, vE, eb, ab, ws);
  k_scan <<<256, 256, 0, stream>>>(Mv0, ws, out);
  k_out  <<<NTOK/TOKA, 256, 0, stream>>>(ws, fb, pW, pb, out);
}